// Round 2
// baseline (690.410 us; speedup 1.0000x reference)
//
#include <hip/hip_runtime.h>
#include <hip/hip_bf16.h>

#define NID  16
#define BB   4
#define HH   192
#define WW   192
#define DHW  1179648          // 32*192*192
#define KB   256              // lovasz buckets over e in [0,2]

// pass1 chunking: 1024 blocks (4/CU), each wave-half covers the chunk for 8 ids
#define P1_CHUNKS 256
#define P1_CHUNK  4608        // DHW / 256
#define P1_ITERS  36          // P1_CHUNK / 128 (two 128-thread id-halves)

// pass3 chunking
#define P3_CHUNKS 128
#define P3_CHUNK  9216        // DHW / 128
#define SUBT      4
#define SUBN      2304        // P3_CHUNK / SUBT
#define SUBIT     9           // SUBN / 256

// workspace layout (float indices)
#define WS_STATS 0            // [64][8]: cnt, Sx, Sy, Sz, s0, s1, s2, ssq
#define WS_FIN   512          // [64][8]: cx, cy, cz, e0, e1, e2, var, exists
#define WS_BG    1024         // [4]
#define WS_SEEDB 1028         // [4] per-batch seed loss
#define WS_INSTL 1032         // [64]
#define WS_HIST  1104         // [64][2][KB] floats: cntF, cntB
#define WS_TOTAL (1104 + 64*2*KB)

__device__ __forceinline__ float ftanh(float x) {
    float t = __expf(2.f * x);
    return 1.f - 2.f / (t + 1.f);
}
__device__ __forceinline__ float fsigmoid(float x) {
    return 1.f / (1.f + __expf(-x));
}
// xyzm is a linspace stack: compute from flat index (saves 3 loads/voxel)
__device__ __forceinline__ void xyz_of(int v, float& x, float& y, float& z) {
    int w = v % WW;
    int t = v / WW;
    int h = t % HH;
    int d = t / HH;
    x = (float)w * (1.f / 191.f);
    y = (float)h * (1.f / 191.f);
    z = (float)d * (1.f / 31.f);
}

// ---------------- pass 1: per-(b,id) masked stats + bg_seed ----------------
// Atomic-free hot loop: LDS atomics cost ~150 cy/instr (measured r0/r1), so
// accumulate all 8 stats x 8 ids in VGPRs via predicated fmac.
// tid<128 handles ids 1..8 (+ bg/seed); tid>=128 handles ids 9..16.
// Both halves stream the same voxels (second half's loads hit L1).
__global__ __launch_bounds__(256, 4) void pass1_stats(
    const float* __restrict__ pred, const int* __restrict__ inst,
    const int* __restrict__ labels, float* __restrict__ ws)
{
    const int b    = blockIdx.y;
    const int tid  = threadIdx.x;
    const int half = tid >> 7;          // 0: ids 1..8 (+bg), 1: ids 9..16
    const int l128 = tid & 127;
    const int idb  = half * 8 + 1;      // first id this half handles

    const float* p3 = pred + (size_t)(b * 7 + 3) * DHW;
    const int*   ib = inst   + (size_t)b * DHW;
    const int*   lb = labels + (size_t)b * DHW;

    float acc[8][8];
    #pragma unroll
    for (int q = 0; q < 8; ++q)
        #pragma unroll
        for (int st = 0; st < 8; ++st) acc[q][st] = 0.f;

    float bgacc = 0.f;
    const int v0 = blockIdx.x * P1_CHUNK;
    for (int it = 0; it < P1_ITERS; ++it) {
        const int v = v0 + it * 128 + l128;
        const int id = ib[v];
        const float s0 = p3[v], s1 = p3[DHW + v], s2 = p3[2 * DHW + v];
        float x, y, z; xyz_of(v, x, y, z);
        const float sq = s0 * s0 + s1 * s1 + s2 * s2;
        if (half == 0) {
            const float seed = fsigmoid(p3[3 * DHW + v]);
            if (lb[v] == 0) bgacc += seed * seed;
        }
        const int idx = id - idb;       // match when idx == q (inline-const cmp)
        #pragma unroll
        for (int q = 0; q < 8; ++q) {
            const float m = (idx == q) ? 1.f : 0.f;
            acc[q][0] += m;
            acc[q][1] += m * x;
            acc[q][2] += m * y;
            acc[q][3] += m * z;
            acc[q][4] += m * s0;
            acc[q][5] += m * s1;
            acc[q][6] += m * s2;
            acc[q][7] += m * sq;
        }
    }

    // cross-lane reduce each accumulator, lane 0 of each wave -> global atomic
    #pragma unroll
    for (int q = 0; q < 8; ++q) {
        #pragma unroll
        for (int st = 0; st < 8; ++st) {
            float r = acc[q][st];
            for (int off = 32; off > 0; off >>= 1) r += __shfl_down(r, off, 64);
            if ((tid & 63) == 0 && r != 0.f)
                atomicAdd(&ws[WS_STATS + (b * NID + (idb - 1 + q)) * 8 + st], r);
        }
    }
    if (half == 0) {
        float r = bgacc;
        for (int off = 32; off > 0; off >>= 1) r += __shfl_down(r, off, 64);
        if ((tid & 63) == 0) atomicAdd(&ws[WS_BG + b], r);
    }
}

// ---------------- pass 2: finalize per-(b,id) stats ----------------
__global__ void pass2_fin(float* __restrict__ ws)
{
    const int t = threadIdx.x;
    if (t >= 64) return;
    const float* s = ws + WS_STATS + t * 8;
    const float cnt = s[0];
    const float exists = (cnt > 0.f) ? 1.f : 0.f;
    const float safe = fmaxf(cnt, 1.f);
    const float m0 = s[4] / safe, m1 = s[5] / safe, m2 = s[6] / safe;
    float* f = ws + WS_FIN + t * 8;
    f[0] = s[1] / safe; f[1] = s[2] / safe; f[2] = s[3] / safe;
    f[3] = __expf(10.f * m0); f[4] = __expf(10.f * m1); f[5] = __expf(10.f * m2);
    f[6] = (s[7] - cnt * (m0 * m0 + m1 * m1 + m2 * m2)) / (3.f * safe);
    f[7] = exists;
}

// ---------------- pass 3: staged se + count-only histograms ----------------
__global__ __launch_bounds__(256) void pass3_hist(
    const float* __restrict__ pred, const int* __restrict__ inst,
    float* __restrict__ ws)
{
    __shared__ float4 sev[SUBN];              // 36.9 KB staged (se0,se1,se2,seed|id)
    __shared__ unsigned cntFB[2][NID][KB];    // 32 KB: x2 half-wave replicas; lo16 FG, hi16 BG
    __shared__ float ctrs[NID][8];
    __shared__ float sred[4];

    const int b   = blockIdx.y;
    const int tid = threadIdx.x;
    const int rep = (tid >> 5) & 1;           // half-wave replica

    for (int i = tid; i < 2 * NID * KB; i += 256) ((unsigned*)cntFB)[i] = 0u;
    if (tid < NID * 8) ((float*)ctrs)[tid] = ws[WS_FIN + b * NID * 8 + tid];
    __syncthreads();

    const float* pb = pred + (size_t)b * 7 * DHW;
    const int*   ib = inst + (size_t)b * DHW;

    float sacc = 0.f;
    const int base0 = blockIdx.x * P3_CHUNK;

    for (int sub = 0; sub < SUBT; ++sub) {
        const int vb = base0 + sub * SUBN;
        // ---- phase A: stage se / seed / id ----
        for (int it = 0; it < SUBIT; ++it) {
            const int i = it * 256 + tid;
            const int v = vb + i;
            float x, y, z; xyz_of(v, x, y, z);
            const float se0 = ftanh(pb[v])           + x;
            const float se1 = ftanh(pb[DHW + v])     + y;
            const float se2 = ftanh(pb[2 * DHW + v]) + z;
            const float seed = fsigmoid(pb[6 * DHW + v]);
            const unsigned id = (unsigned)ib[v];
            // pack instance id into low 8 mantissa bits of seed (|err| < 2^-16)
            const unsigned sw = (__float_as_uint(seed) & ~0xFFu) | id;
            sev[i] = make_float4(se0, se1, se2, __uint_as_float(sw));
        }
        __syncthreads();
        // ---- phase B: instances in groups of 4, centers in registers ----
        for (int g = 0; g < 4; ++g) {
            float cx[4], cy[4], cz[4], e0[4], e1[4], e2[4];
            int exq[4];
            #pragma unroll
            for (int qi = 0; qi < 4; ++qi) {
                const int iid = g * 4 + qi;
                cx[qi] = ctrs[iid][0]; cy[qi] = ctrs[iid][1]; cz[qi] = ctrs[iid][2];
                e0[qi] = ctrs[iid][3]; e1[qi] = ctrs[iid][4]; e2[qi] = ctrs[iid][5];
                exq[qi] = (ctrs[iid][7] != 0.f);
            }
            for (int it = 0; it < SUBIT; ++it) {
                const int i = it * 256 + tid;
                const float4 s = sev[i];
                const unsigned sw = __float_as_uint(s.w);
                const int id = (int)(sw & 0xFFu);
                const float seed = s.w;
                #pragma unroll
                for (int qi = 0; qi < 4; ++qi) {
                    if (!exq[qi]) continue;
                    const int iid = g * 4 + qi;
                    const float d0 = s.x - cx[qi];
                    const float d1 = s.y - cy[qi];
                    const float d2 = s.z - cz[qi];
                    const float q2 = d0 * d0 * e0[qi] + d1 * d1 * e1[qi] + d2 * d2 * e2[qi];
                    const float dist = __expf(-q2);
                    const bool m = (id == iid + 1);
                    const float e = m ? (2.f - 2.f * dist) : (2.f * dist);
                    int k = (int)(e * 128.f);
                    k = min(max(k, 0), KB - 1);
                    // BG in bucket 0 contributes exactly 0 -> skip
                    const unsigned val = m ? 1u : (k ? 0x10000u : 0u);
                    if (m) { const float ds = seed - dist; sacc += ds * ds; }
                    if (val) atomicAdd(&cntFB[rep][iid][k], val);
                }
            }
        }
        __syncthreads();   // also guards cntFB before the merge below
    }

    // merge packed LDS counts (both replicas) -> global float histograms
    float* gh = ws + WS_HIST;
    for (int i = tid; i < NID * KB; i += 256) {
        const int iid = i >> 8, k = i & (KB - 1);
        const unsigned c = cntFB[0][iid][k] + cntFB[1][iid][k];  // fields < 2^15 each: no carry
        float* basep = gh + (size_t)(b * NID + iid) * 2 * KB;
        const float cf = (float)(c & 0xFFFFu);
        const float cb = (float)(c >> 16);
        if (cf != 0.f) atomicAdd(&basep[k], cf);
        if (cb != 0.f) atomicAdd(&basep[KB + k], cb);
    }
    // per-batch seed loss reduce
    float v = sacc;
    for (int off = 32; off > 0; off >>= 1) v += __shfl_down(v, off, 64);
    if ((tid & 63) == 0) sred[tid >> 6] = v;
    __syncthreads();
    if (tid == 0) atomicAdd(&ws[WS_SEEDB + b], sred[0] + sred[1] + sred[2] + sred[3]);
}

// ---------------- pass 4: lovasz from count histograms (midpoint e) ----------------
__global__ __launch_bounds__(256) void pass4_lovasz(float* __restrict__ ws)
{
    const int t = blockIdx.x;    // (b*16 + iid)
    const int j = threadIdx.x;   // j=0 <-> highest-error bucket
    __shared__ float sF[KB], sB[KB];
    __shared__ double red[KB];

    const float P = ws[WS_STATS + t * 8];
    const float exists = ws[WS_FIN + t * 8 + 7];
    const float* gh = ws + WS_HIST + (size_t)t * 2 * KB;

    const int k = KB - 1 - j;
    const float nF = gh[k], nB = gh[KB + k];
    const float mid = ((float)k + 0.5f) * (1.f / 128.f);
    const float rF = nF * mid, rB = nB * mid;

    sF[j] = nF; sB[j] = nB;
    __syncthreads();
    for (int off = 1; off < KB; off <<= 1) {
        float a = 0.f, c = 0.f;
        if (j >= off) { a = sF[j - off]; c = sB[j - off]; }
        __syncthreads();
        sF[j] += a; sB[j] += c;
        __syncthreads();
    }
    double contrib = 0.0;
    if (exists != 0.f && P > 0.f) {
        const double Bb = (double)sB[j] - (double)nB;
        const double U0 = (double)P + Bb;
        const double Fafter = (double)sF[j];
        contrib = (double)rF / U0
                + (double)rB * ((double)P - Fafter) / (U0 * (U0 + (double)nB));
    }
    red[j] = contrib;
    __syncthreads();
    for (int off = KB / 2; off > 0; off >>= 1) {
        if (j < off) red[j] += red[j + off];
        __syncthreads();
    }
    if (j == 0) ws[WS_INSTL + t] = (float)red[0];
}

// ---------------- pass 5: final assembly (parallel over batches) ----------------
__global__ void pass5_final(const float* __restrict__ ws, float* __restrict__ out)
{
    const int t = threadIdx.x;   // 64 threads
    __shared__ float pl[3][4];
    if (t < 4) {
        float obj = 0.f, v = 0.f, i2 = 0.f;
        for (int i = 0; i < NID; ++i) {
            const int u = t * NID + i;
            const float ex = ws[WS_FIN + u * 8 + 7];
            obj += ex;
            v   += ws[WS_FIN + u * 8 + 6] * ex;
            i2  += ws[WS_INSTL + u];
        }
        const float denom = fmaxf(obj, 1.f);
        pl[0][t] = i2 / denom;
        pl[1][t] = v / denom;
        pl[2][t] = (ws[WS_SEEDB + t] + ws[WS_BG + t]) / (float)DHW;
    }
    __syncthreads();
    if (t == 0) {
        const float linst = (pl[0][0] + pl[0][1] + pl[0][2] + pl[0][3]) * (1.0f / BB);
        const float lvar  = (pl[1][0] + pl[1][1] + pl[1][2] + pl[1][3]) * (10.0f / BB);
        const float lseed = (pl[2][0] + pl[2][1] + pl[2][2] + pl[2][3]) * (1.0f / BB);
        out[0] = linst;
        out[1] = lvar;
        out[2] = lseed;
        out[3] = linst + lvar + lseed;
    }
}

extern "C" void kernel_launch(void* const* d_in, const int* in_sizes, int n_in,
                              void* d_out, int out_size, void* d_ws, size_t ws_size,
                              hipStream_t stream)
{
    const float* pred   = (const float*)d_in[0];
    const int*   inst   = (const int*)  d_in[1];
    const int*   labels = (const int*)  d_in[2];
    // d_in[3] = center_images (unused), d_in[4] = xyzm (computed analytically)
    float* ws  = (float*)d_ws;
    float* out = (float*)d_out;

    hipMemsetAsync(d_ws, 0, (size_t)WS_TOTAL * sizeof(float), stream);

    dim3 grid1(P1_CHUNKS, BB);
    dim3 grid3(P3_CHUNKS, BB);
    pass1_stats<<<grid1, 256, 0, stream>>>(pred, inst, labels, ws);
    pass2_fin  <<<1, 64, 0, stream>>>(ws);
    pass3_hist <<<grid3, 256, 0, stream>>>(pred, inst, ws);
    pass4_lovasz<<<64, KB, 0, stream>>>(ws);
    pass5_final<<<1, 64, 0, stream>>>(ws, out);
}

// Round 3
// 580.520 us; speedup vs baseline: 1.1893x; 1.1893x over previous
//
#include <hip/hip_runtime.h>

#define NID  16
#define BB   4
#define HH   192
#define WW   192
#define DHW  1179648          // 32*192*192
#define KB   256              // lovasz buckets over e in [0,2]

// pass1 chunking: 2048 blocks (8/CU), 4 waves/block, each wave covers the
// chunk for (id-half x stat-half); 36 iters of 64 lanes = 2304 voxels
#define P1_CHUNKS 512
#define P1_CHUNK  2304        // DHW / 512
#define P1_ITERS  36          // P1_CHUNK / 64

// pass3 chunking
#define P3_CHUNKS 128
#define P3_CHUNK  9216        // DHW / 128
#define SUBT      4
#define SUBN      2304        // P3_CHUNK / SUBT
#define SUBIT     9           // SUBN / 256

// workspace layout (float indices)
#define WS_STATS 0            // [64][8]: cnt, Sx, Sy, Sz, s0, s1, s2, ssq
#define WS_FIN   512          // (unused; kept for layout stability)
#define WS_BG    1024         // [4]
#define WS_SEEDB 1028         // [4] per-batch seed loss
#define WS_INSTL 1032         // [64]
#define WS_HIST  1104         // [64][2][KB] floats: cntF, cntB
#define WS_TOTAL (1104 + 64*2*KB)

__device__ __forceinline__ float ftanh(float x) {
    float t = __expf(2.f * x);
    return 1.f - 2.f / (t + 1.f);
}
__device__ __forceinline__ float fsigmoid(float x) {
    return 1.f / (1.f + __expf(-x));
}
// xyzm is a linspace stack: compute from flat index (saves 3 loads/voxel)
__device__ __forceinline__ void xyz_of(int v, float& x, float& y, float& z) {
    int w = v % WW;
    int t = v / WW;
    int h = t % HH;
    int d = t / HH;
    x = (float)w * (1.f / 191.f);
    y = (float)h * (1.f / 191.f);
    z = (float)d * (1.f / 31.f);
}

// ---------------- pass 1: per-(b,id) masked stats + bg_seed ----------------
// Atomic-free, register-resident accumulation. 4 waves per block:
//   wave 0: ids 1..8  geometry (cnt,Sx,Sy,Sz) int-packed + bg_seed
//   wave 1: ids 9..16 geometry
//   wave 2: ids 1..8  sigma (s0,s1,s2,ssq) floats
//   wave 3: ids 9..16 sigma
// Max live accumulator array = 32 floats (waves 2/3) -> stays in VGPRs
// (r2 lesson: 64-float acc + launch_bounds minwaves spilled to scratch,
//  WRITE_SIZE 8.2 MB, 383 us).
__global__ __launch_bounds__(256) void pass1_stats(
    const float* __restrict__ pred, const int* __restrict__ inst,
    const int* __restrict__ labels, float* __restrict__ ws)
{
    const int b    = blockIdx.y;
    const int tid  = threadIdx.x;
    const int wv   = tid >> 6;          // 0..3
    const int lane = tid & 63;
    const int half = wv & 1;            // 0: ids 1..8, 1: ids 9..16
    const int idb  = half * 8 + 1;

    const float* p3 = pred + (size_t)(b * 7 + 3) * DHW;
    const int*   ib = inst   + (size_t)b * DHW;
    const int*   lb = labels + (size_t)b * DHW;

    const int v0 = blockIdx.x * P1_CHUNK;

    if (wv < 2) {
        // ---- geometry waves: packed ints g0 = Sw | cnt<<17, g1 = Sh | Sd<<17
        unsigned g0[8], g1[8];
        #pragma unroll
        for (int q = 0; q < 8; ++q) { g0[q] = 0u; g1[q] = 0u; }
        float bgacc = 0.f;
        for (int it = 0; it < P1_ITERS; ++it) {
            const int v = v0 + it * 64 + lane;
            const int id = ib[v];
            if (wv == 0) {
                const float seed = fsigmoid(p3[3 * DHW + v]);
                if (lb[v] == 0) bgacc += seed * seed;
            }
            const int w  = v % WW;
            const int t2 = v / WW;
            const int h  = t2 % HH;
            const int d  = t2 / HH;
            const unsigned p0 = (unsigned)w | (1u << 17);
            const unsigned p1 = (unsigned)h | ((unsigned)d << 17);
            const int idx = id - idb;
            #pragma unroll
            for (int q = 0; q < 8; ++q) {
                const bool e = (idx == q);
                g0[q] += e ? p0 : 0u;
                g1[q] += e ? p1 : 0u;
            }
        }
        #pragma unroll
        for (int q = 0; q < 8; ++q) {
            float c  = (float)(g0[q] >> 17);
            float sx = (float)(g0[q] & 0x1FFFFu) * (1.f / 191.f);
            float sy = (float)(g1[q] & 0x1FFFFu) * (1.f / 191.f);
            float sz = (float)(g1[q] >> 17)      * (1.f / 31.f);
            for (int off = 32; off > 0; off >>= 1) {
                c  += __shfl_down(c,  off, 64);
                sx += __shfl_down(sx, off, 64);
                sy += __shfl_down(sy, off, 64);
                sz += __shfl_down(sz, off, 64);
            }
            if (lane == 0 && c != 0.f) {
                float* dst = ws + WS_STATS + (size_t)(b * NID + (idb - 1 + q)) * 8;
                atomicAdd(&dst[0], c);
                atomicAdd(&dst[1], sx);
                atomicAdd(&dst[2], sy);
                atomicAdd(&dst[3], sz);
            }
        }
        if (wv == 0) {
            float r = bgacc;
            for (int off = 32; off > 0; off >>= 1) r += __shfl_down(r, off, 64);
            if (lane == 0) atomicAdd(&ws[WS_BG + b], r);
        }
    } else {
        // ---- sigma waves: 4 float accumulators per id
        float a0[8], a1[8], a2[8], a3[8];
        #pragma unroll
        for (int q = 0; q < 8; ++q) { a0[q] = 0.f; a1[q] = 0.f; a2[q] = 0.f; a3[q] = 0.f; }
        for (int it = 0; it < P1_ITERS; ++it) {
            const int v = v0 + it * 64 + lane;
            const int id = ib[v];
            const float s0 = p3[v], s1 = p3[DHW + v], s2 = p3[2 * DHW + v];
            const float sq = s0 * s0 + s1 * s1 + s2 * s2;
            const int idx = id - idb;
            #pragma unroll
            for (int q = 0; q < 8; ++q) {
                const float m = (idx == q) ? 1.f : 0.f;
                a0[q] = fmaf(m, s0, a0[q]);
                a1[q] = fmaf(m, s1, a1[q]);
                a2[q] = fmaf(m, s2, a2[q]);
                a3[q] = fmaf(m, sq, a3[q]);
            }
        }
        #pragma unroll
        for (int q = 0; q < 8; ++q) {
            float r0 = a0[q], r1 = a1[q], r2 = a2[q], r3 = a3[q];
            for (int off = 32; off > 0; off >>= 1) {
                r0 += __shfl_down(r0, off, 64);
                r1 += __shfl_down(r1, off, 64);
                r2 += __shfl_down(r2, off, 64);
                r3 += __shfl_down(r3, off, 64);
            }
            if (lane == 0 && r3 != 0.f) {
                float* dst = ws + WS_STATS + (size_t)(b * NID + (idb - 1 + q)) * 8;
                atomicAdd(&dst[4], r0);
                atomicAdd(&dst[5], r1);
                atomicAdd(&dst[6], r2);
                atomicAdd(&dst[7], r3);
            }
        }
    }
}

// ---------------- pass 3: staged se + count-only histograms ----------------
// (pass2 folded into the prologue: each block finalizes its batch's 16
//  instances from WS_STATS directly -> one fewer kernel launch)
__global__ __launch_bounds__(256) void pass3_hist(
    const float* __restrict__ pred, const int* __restrict__ inst,
    float* __restrict__ ws)
{
    __shared__ float4 sev[SUBN];              // 36.9 KB staged (se0,se1,se2,seed|id)
    __shared__ unsigned cntFB[2][NID][KB];    // 32 KB: x2 half-wave replicas; lo16 FG, hi16 BG
    __shared__ float ctrs[NID][8];
    __shared__ float sred[4];

    const int b   = blockIdx.y;
    const int tid = threadIdx.x;
    const int rep = (tid >> 5) & 1;           // half-wave replica

    for (int i = tid; i < 2 * NID * KB; i += 256) ((unsigned*)cntFB)[i] = 0u;
    if (tid < NID) {
        const float* s = ws + WS_STATS + (size_t)(b * NID + tid) * 8;
        const float cnt = s[0];
        const float safe = fmaxf(cnt, 1.f);
        const float m0 = s[4] / safe, m1 = s[5] / safe, m2 = s[6] / safe;
        ctrs[tid][0] = s[1] / safe;
        ctrs[tid][1] = s[2] / safe;
        ctrs[tid][2] = s[3] / safe;
        ctrs[tid][3] = __expf(10.f * m0);
        ctrs[tid][4] = __expf(10.f * m1);
        ctrs[tid][5] = __expf(10.f * m2);
        ctrs[tid][6] = 0.f;
        ctrs[tid][7] = (cnt > 0.f) ? 1.f : 0.f;
    }
    __syncthreads();

    const float* pb = pred + (size_t)b * 7 * DHW;
    const int*   ib = inst + (size_t)b * DHW;

    float sacc = 0.f;
    const int base0 = blockIdx.x * P3_CHUNK;

    for (int sub = 0; sub < SUBT; ++sub) {
        const int vb = base0 + sub * SUBN;
        // ---- phase A: stage se / seed / id ----
        for (int it = 0; it < SUBIT; ++it) {
            const int i = it * 256 + tid;
            const int v = vb + i;
            float x, y, z; xyz_of(v, x, y, z);
            const float se0 = ftanh(pb[v])           + x;
            const float se1 = ftanh(pb[DHW + v])     + y;
            const float se2 = ftanh(pb[2 * DHW + v]) + z;
            const float seed = fsigmoid(pb[6 * DHW + v]);
            const unsigned id = (unsigned)ib[v];
            // pack instance id into low 8 mantissa bits of seed (|err| < 2^-16)
            const unsigned sw = (__float_as_uint(seed) & ~0xFFu) | id;
            sev[i] = make_float4(se0, se1, se2, __uint_as_float(sw));
        }
        __syncthreads();
        // ---- phase B: instances in groups of 4, centers in registers ----
        for (int g = 0; g < 4; ++g) {
            float cx[4], cy[4], cz[4], e0[4], e1[4], e2[4];
            int exq[4];
            #pragma unroll
            for (int qi = 0; qi < 4; ++qi) {
                const int iid = g * 4 + qi;
                cx[qi] = ctrs[iid][0]; cy[qi] = ctrs[iid][1]; cz[qi] = ctrs[iid][2];
                e0[qi] = ctrs[iid][3]; e1[qi] = ctrs[iid][4]; e2[qi] = ctrs[iid][5];
                exq[qi] = (ctrs[iid][7] != 0.f);
            }
            for (int it = 0; it < SUBIT; ++it) {
                const int i = it * 256 + tid;
                const float4 s = sev[i];
                const unsigned sw = __float_as_uint(s.w);
                const int id = (int)(sw & 0xFFu);
                const float seed = s.w;
                #pragma unroll
                for (int qi = 0; qi < 4; ++qi) {
                    if (!exq[qi]) continue;
                    const int iid = g * 4 + qi;
                    const float d0 = s.x - cx[qi];
                    const float d1 = s.y - cy[qi];
                    const float d2 = s.z - cz[qi];
                    const float q2 = d0 * d0 * e0[qi] + d1 * d1 * e1[qi] + d2 * d2 * e2[qi];
                    const float dist = __expf(-q2);
                    const bool m = (id == iid + 1);
                    const float e = m ? (2.f - 2.f * dist) : (2.f * dist);
                    int k = (int)(e * 128.f);
                    k = min(max(k, 0), KB - 1);
                    // BG in bucket 0 contributes exactly 0 -> skip
                    const unsigned val = m ? 1u : (k ? 0x10000u : 0u);
                    if (m) { const float ds = seed - dist; sacc += ds * ds; }
                    if (val) atomicAdd(&cntFB[rep][iid][k], val);
                }
            }
        }
        __syncthreads();   // also guards cntFB before the merge below
    }

    // merge packed LDS counts (both replicas) -> global float histograms
    float* gh = ws + WS_HIST;
    for (int i = tid; i < NID * KB; i += 256) {
        const int iid = i >> 8, k = i & (KB - 1);
        const unsigned c = cntFB[0][iid][k] + cntFB[1][iid][k];  // fields < 2^15 each: no carry
        float* basep = gh + (size_t)(b * NID + iid) * 2 * KB;
        const float cf = (float)(c & 0xFFFFu);
        const float cb = (float)(c >> 16);
        if (cf != 0.f) atomicAdd(&basep[k], cf);
        if (cb != 0.f) atomicAdd(&basep[KB + k], cb);
    }
    // per-batch seed loss reduce
    float v = sacc;
    for (int off = 32; off > 0; off >>= 1) v += __shfl_down(v, off, 64);
    if ((tid & 63) == 0) sred[tid >> 6] = v;
    __syncthreads();
    if (tid == 0) atomicAdd(&ws[WS_SEEDB + b], sred[0] + sred[1] + sred[2] + sred[3]);
}

// ---------------- pass 4: lovasz from count histograms (midpoint e) ----------------
__global__ __launch_bounds__(256) void pass4_lovasz(float* __restrict__ ws)
{
    const int t = blockIdx.x;    // (b*16 + iid)
    const int j = threadIdx.x;   // j=0 <-> highest-error bucket
    __shared__ float sF[KB], sB[KB];
    __shared__ double red[KB];

    const float P = ws[WS_STATS + t * 8];
    const float* gh = ws + WS_HIST + (size_t)t * 2 * KB;

    const int k = KB - 1 - j;
    const float nF = gh[k], nB = gh[KB + k];
    const float mid = ((float)k + 0.5f) * (1.f / 128.f);
    const float rF = nF * mid, rB = nB * mid;

    sF[j] = nF; sB[j] = nB;
    __syncthreads();
    for (int off = 1; off < KB; off <<= 1) {
        float a = 0.f, c = 0.f;
        if (j >= off) { a = sF[j - off]; c = sB[j - off]; }
        __syncthreads();
        sF[j] += a; sB[j] += c;
        __syncthreads();
    }
    double contrib = 0.0;
    if (P > 0.f) {   // exists == (cnt > 0)
        const double Bb = (double)sB[j] - (double)nB;
        const double U0 = (double)P + Bb;
        const double Fafter = (double)sF[j];
        contrib = (double)rF / U0
                + (double)rB * ((double)P - Fafter) / (U0 * (U0 + (double)nB));
    }
    red[j] = contrib;
    __syncthreads();
    for (int off = KB / 2; off > 0; off >>= 1) {
        if (j < off) red[j] += red[j + off];
        __syncthreads();
    }
    if (j == 0) ws[WS_INSTL + t] = (float)red[0];
}

// ---------------- pass 5: final assembly (parallel over batches) ----------------
__global__ void pass5_final(const float* __restrict__ ws, float* __restrict__ out)
{
    const int t = threadIdx.x;   // 64 threads
    __shared__ float pl[3][4];
    if (t < 4) {
        float obj = 0.f, v = 0.f, i2 = 0.f;
        for (int i = 0; i < NID; ++i) {
            const int u = t * NID + i;
            const float* s = ws + WS_STATS + (size_t)u * 8;
            const float cnt = s[0];
            i2 += ws[WS_INSTL + u];
            if (cnt > 0.f) {
                obj += 1.f;
                const float m0 = s[4] / cnt, m1 = s[5] / cnt, m2 = s[6] / cnt;
                v += (s[7] - cnt * (m0 * m0 + m1 * m1 + m2 * m2)) / (3.f * cnt);
            }
        }
        const float denom = fmaxf(obj, 1.f);
        pl[0][t] = i2 / denom;
        pl[1][t] = v / denom;
        pl[2][t] = (ws[WS_SEEDB + t] + ws[WS_BG + t]) / (float)DHW;
    }
    __syncthreads();
    if (t == 0) {
        const float linst = (pl[0][0] + pl[0][1] + pl[0][2] + pl[0][3]) * (1.0f / BB);
        const float lvar  = (pl[1][0] + pl[1][1] + pl[1][2] + pl[1][3]) * (10.0f / BB);
        const float lseed = (pl[2][0] + pl[2][1] + pl[2][2] + pl[2][3]) * (1.0f / BB);
        out[0] = linst;
        out[1] = lvar;
        out[2] = lseed;
        out[3] = linst + lvar + lseed;
    }
}

extern "C" void kernel_launch(void* const* d_in, const int* in_sizes, int n_in,
                              void* d_out, int out_size, void* d_ws, size_t ws_size,
                              hipStream_t stream)
{
    const float* pred   = (const float*)d_in[0];
    const int*   inst   = (const int*)  d_in[1];
    const int*   labels = (const int*)  d_in[2];
    // d_in[3] = center_images (unused), d_in[4] = xyzm (computed analytically)
    float* ws  = (float*)d_ws;
    float* out = (float*)d_out;

    hipMemsetAsync(d_ws, 0, (size_t)WS_TOTAL * sizeof(float), stream);

    dim3 grid1(P1_CHUNKS, BB);
    dim3 grid3(P3_CHUNKS, BB);
    pass1_stats<<<grid1, 256, 0, stream>>>(pred, inst, labels, ws);
    pass3_hist <<<grid3, 256, 0, stream>>>(pred, inst, ws);
    pass4_lovasz<<<64, KB, 0, stream>>>(ws);
    pass5_final<<<1, 64, 0, stream>>>(ws, out);
}

// Round 4
// 352.250 us; speedup vs baseline: 1.9600x; 1.6480x over previous
//
#include <hip/hip_runtime.h>

#define NID  16
#define BB   4
#define HH   192
#define WW   192
#define DHW  1179648          // 32*192*192
#define KB   256              // lovasz buckets over e in [0,2]

// pass1: grid (256, BB); chunk = 24 rows of 192 = 4608 voxels; 72 iters of 64
#define P1_ROWS   24
#define P1_ITERS  72

// pass3 chunking
#define P3_CHUNKS 128
#define P3_CHUNK  9216        // DHW / 128
#define SUBT      4
#define SUBN      2304        // P3_CHUNK / SUBT
#define SUBIT     9           // SUBN / 256

// workspace layout (float indices)
#define WS_STATS 0            // [64][8]: cnt, Sx, Sy, Sz, s0, s1, s2, ssq
#define WS_BG8   512          // [4][8] spread slots (same-line atomic chains /8)
#define WS_SEED8 544          // [4][8]
#define WS_INSTL 576          // [64]
#define WS_HIST  640          // [64][2][KB] floats: cntF, cntB
#define WS_TOTAL (640 + 64*2*KB)

__device__ __forceinline__ float ftanh(float x) {
    float t = __expf(2.f * x);
    return 1.f - 2.f / (t + 1.f);
}
__device__ __forceinline__ float fsigmoid(float x) {
    return 1.f / (1.f + __expf(-x));
}
__device__ __forceinline__ float wred(float v) {
    for (int off = 32; off > 0; off >>= 1) v += __shfl_down(v, off, 64);
    return v;
}
// xyzm is a linspace stack: compute from flat index
__device__ __forceinline__ void xyz_of(int v, float& x, float& y, float& z) {
    int w = v % WW;
    int t = v / WW;
    int h = t % HH;
    int d = t / HH;
    x = (float)w * (1.f / 191.f);
    y = (float)h * (1.f / 191.f);
    z = (float)d * (1.f / 31.f);
}

#define REP8(M) M(0) M(1) M(2) M(3) M(4) M(5) M(6) M(7)

// ---------------- pass 1: per-(b,id) masked stats + bg_seed ----------------
// Hot loop: named-scalar register accumulation (no arrays -> no SROA risk).
// Epilogue: per-wave shuffle reduce -> LDS block partial (disjoint slots per
// wave) -> ONE wave-coalesced global atomic of 128 consecutive floats.
// (r3 lesson: 262K lane0-serial scalar atomics onto 32 lines = ~8K-deep
//  memory-side line-RMW chains ~ 245 us. Coalesced: 8 line-RMWs/block.)
__global__ __launch_bounds__(256) void pass1_stats(
    const float* __restrict__ pred, const int* __restrict__ inst,
    const int* __restrict__ labels, float* __restrict__ ws)
{
    __shared__ float part[128];         // [id 0..15][st 0..7] block partials
    const int b    = blockIdx.y;
    const int tid  = threadIdx.x;
    const int wv   = tid >> 6;          // 0..3
    const int lane = tid & 63;
    const int idb0 = (wv & 1) * 8;      // 0-based first id of this wave's half

    const float* p3 = pred + (size_t)(b * 7 + 3) * DHW;
    const int*   ib = inst   + (size_t)b * DHW;
    const int*   lb = labels + (size_t)b * DHW;
    const int row0 = blockIdx.x * P1_ROWS;

    if (wv < 2) {
        // geometry waves: packed ints G0=Sw|cnt<<17, G1=Sh|Sd<<17 per id.
        // ranges (72 iters): cnt<=72, Sw,Sh<=13752<2^17, Sd<=2232 -> exact.
        unsigned G00=0u,G01=0u,G02=0u,G03=0u,G04=0u,G05=0u,G06=0u,G07=0u;
        unsigned G10=0u,G11=0u,G12=0u,G13=0u,G14=0u,G15=0u,G16=0u,G17=0u;
        float bgacc = 0.f;
        for (int it = 0; it < P1_ITERS; ++it) {
            const int seg = it % 3, r = it / 3;     // uniform (SALU)
            const int row = row0 + r;
            const int w   = seg * 64 + lane;
            const int v   = row * WW + w;
            const int id  = ib[v];
            if (wv == 0) {
                const float seed = fsigmoid(p3[3 * DHW + v]);
                if (lb[v] == 0) bgacc += seed * seed;
            }
            const unsigned p0 = (unsigned)w | (1u << 17);
            const unsigned p1 = (unsigned)(row % HH) | ((unsigned)(row / HH) << 17);
            const int idx = id - 1 - idb0;
            #define GEO(Q) { const bool e = (idx == Q); \
                             G0##Q += e ? p0 : 0u; G1##Q += e ? p1 : 0u; }
            REP8(GEO)
            #undef GEO
        }
        #define GRED(Q) { \
            float c  = wred((float)(G0##Q >> 17)); \
            float sx = wred((float)(G0##Q & 0x1FFFFu) * (1.f / 191.f)); \
            float sy = wred((float)(G1##Q & 0x1FFFFu) * (1.f / 191.f)); \
            float sz = wred((float)(G1##Q >> 17)      * (1.f / 31.f)); \
            if (lane == 0) { float* pp = &part[(idb0 + Q) * 8]; \
                             pp[0] = c; pp[1] = sx; pp[2] = sy; pp[3] = sz; } }
        REP8(GRED)
        #undef GRED
        if (wv == 0) {
            const float r = wred(bgacc);
            if (lane == 0) atomicAdd(&ws[WS_BG8 + b * 8 + (blockIdx.x & 7)], r);
        }
    } else {
        // sigma waves: 4 float accumulators per id, named scalars
        float SA0=0.f,SA1=0.f,SA2=0.f,SA3=0.f,SA4=0.f,SA5=0.f,SA6=0.f,SA7=0.f;
        float SB0=0.f,SB1=0.f,SB2=0.f,SB3=0.f,SB4=0.f,SB5=0.f,SB6=0.f,SB7=0.f;
        float SC0=0.f,SC1=0.f,SC2=0.f,SC3=0.f,SC4=0.f,SC5=0.f,SC6=0.f,SC7=0.f;
        float SD0=0.f,SD1=0.f,SD2=0.f,SD3=0.f,SD4=0.f,SD5=0.f,SD6=0.f,SD7=0.f;
        for (int it = 0; it < P1_ITERS; ++it) {
            const int seg = it % 3, r = it / 3;
            const int v   = (row0 + r) * WW + seg * 64 + lane;
            const int id  = ib[v];
            const float s0 = p3[v], s1 = p3[DHW + v], s2 = p3[2 * DHW + v];
            const float sq = s0 * s0 + s1 * s1 + s2 * s2;
            const int idx = id - 1 - idb0;
            #define SIG(Q) { const float m = (idx == Q) ? 1.f : 0.f; \
                SA##Q = fmaf(m, s0, SA##Q); SB##Q = fmaf(m, s1, SB##Q); \
                SC##Q = fmaf(m, s2, SC##Q); SD##Q = fmaf(m, sq, SD##Q); }
            REP8(SIG)
            #undef SIG
        }
        #define SRED(Q) { \
            float r0 = wred(SA##Q), r1 = wred(SB##Q); \
            float r2 = wred(SC##Q), r3 = wred(SD##Q); \
            if (lane == 0) { float* pp = &part[(idb0 + Q) * 8 + 4]; \
                             pp[0] = r0; pp[1] = r1; pp[2] = r2; pp[3] = r3; } }
        REP8(SRED)
        #undef SRED
    }
    __syncthreads();
    // one coalesced atomic covering 128 consecutive floats (8 lines/block)
    if (tid < 128) {
        const float pv = part[tid];
        if (pv != 0.f) atomicAdd(&ws[WS_STATS + b * 128 + tid], pv);
    }
}

// ---------------- pass 3: staged se + count-only histograms ----------------
// Lane-rotation over the 4-id group: each atomic instruction's lanes spread
// across 4 different ids' histogram rows -> same-address multiplicity /4.
__global__ __launch_bounds__(256) void pass3_hist(
    const float* __restrict__ pred, const int* __restrict__ inst,
    float* __restrict__ ws)
{
    __shared__ float4 sev[SUBN];              // 36.9 KB staged (se0,se1,se2,seed|id)
    __shared__ unsigned cntFB[2][NID][KB];    // 32 KB: x2 half-wave replicas
    __shared__ float ctrs[NID][8];
    __shared__ float sred[4];

    const int b   = blockIdx.y;
    const int tid = threadIdx.x;
    const int rep = (tid >> 5) & 1;           // half-wave replica
    const int rot = tid & 3;                  // per-lane id rotation

    for (int i = tid; i < 2 * NID * KB; i += 256) ((unsigned*)cntFB)[i] = 0u;
    if (tid < NID) {
        const float* s = ws + WS_STATS + (size_t)(b * NID + tid) * 8;
        const float cnt = s[0];
        const float safe = fmaxf(cnt, 1.f);
        const float m0 = s[4] / safe, m1 = s[5] / safe, m2 = s[6] / safe;
        ctrs[tid][0] = s[1] / safe;
        ctrs[tid][1] = s[2] / safe;
        ctrs[tid][2] = s[3] / safe;
        ctrs[tid][3] = __expf(10.f * m0);
        ctrs[tid][4] = __expf(10.f * m1);
        ctrs[tid][5] = __expf(10.f * m2);
        ctrs[tid][6] = 0.f;
        ctrs[tid][7] = (cnt > 0.f) ? 1.f : 0.f;
    }
    __syncthreads();

    const float* pb = pred + (size_t)b * 7 * DHW;
    const int*   ib = inst + (size_t)b * DHW;

    float sacc = 0.f;
    const int base0 = blockIdx.x * P3_CHUNK;

    for (int sub = 0; sub < SUBT; ++sub) {
        const int vb = base0 + sub * SUBN;
        // ---- phase A: stage se / seed / id ----
        for (int it = 0; it < SUBIT; ++it) {
            const int i = it * 256 + tid;
            const int v = vb + i;
            float x, y, z; xyz_of(v, x, y, z);
            const float se0 = ftanh(pb[v])           + x;
            const float se1 = ftanh(pb[DHW + v])     + y;
            const float se2 = ftanh(pb[2 * DHW + v]) + z;
            const float seed = fsigmoid(pb[6 * DHW + v]);
            const unsigned id = (unsigned)ib[v];
            // pack instance id into low 8 mantissa bits of seed (|err| < 2^-16)
            const unsigned sw = (__float_as_uint(seed) & ~0xFFu) | id;
            sev[i] = make_float4(se0, se1, se2, __uint_as_float(sw));
        }
        __syncthreads();
        // ---- phase B: 4 groups of 4 ids, lane-rotated within group ----
        for (int g = 0; g < 4; ++g) {
            float cx[4], cy[4], cz[4], e0[4], e1[4], e2[4];
            int iidq[4];
            #pragma unroll
            for (int s = 0; s < 4; ++s) {
                const int iid = g * 4 + ((s + rot) & 3);
                iidq[s] = iid;
                cx[s] = ctrs[iid][0]; cy[s] = ctrs[iid][1]; cz[s] = ctrs[iid][2];
                e0[s] = ctrs[iid][3]; e1[s] = ctrs[iid][4]; e2[s] = ctrs[iid][5];
            }
            for (int it = 0; it < SUBIT; ++it) {
                const int i = it * 256 + tid;
                const float4 sv = sev[i];
                const unsigned sw = __float_as_uint(sv.w);
                const int id = (int)(sw & 0xFFu);
                const float seed = sv.w;
                #pragma unroll
                for (int s = 0; s < 4; ++s) {
                    const float d0 = sv.x - cx[s];
                    const float d1 = sv.y - cy[s];
                    const float d2 = sv.z - cz[s];
                    const float q2 = d0 * d0 * e0[s] + d1 * d1 * e1[s] + d2 * d2 * e2[s];
                    const float dist = __expf(-q2);
                    const bool m = (id == iidq[s] + 1);
                    const float e = m ? (2.f - 2.f * dist) : (2.f * dist);
                    int k = (int)(e * 128.f);
                    k = min(max(k, 0), KB - 1);
                    // BG in bucket 0 contributes exactly 0 -> skip
                    const unsigned val = m ? 1u : (k ? 0x10000u : 0u);
                    if (m) { const float ds = seed - dist; sacc += ds * ds; }
                    if (val) atomicAdd(&cntFB[rep][iidq[s]][k], val);
                }
            }
        }
        __syncthreads();   // also guards cntFB before the merge below
    }

    // merge packed LDS counts (both replicas) -> global float histograms
    float* gh = ws + WS_HIST;
    for (int i = tid; i < NID * KB; i += 256) {
        const int iid = i >> 8, k = i & (KB - 1);
        const unsigned c = cntFB[0][iid][k] + cntFB[1][iid][k];  // fields < 2^15: no carry
        float* basep = gh + (size_t)(b * NID + iid) * 2 * KB;
        const float cf = (float)(c & 0xFFFFu);
        const float cb = (float)(c >> 16);
        if (cf != 0.f) atomicAdd(&basep[k], cf);
        if (cb != 0.f) atomicAdd(&basep[KB + k], cb);
    }
    // per-batch seed loss reduce (spread over 8 slots)
    float v = sacc;
    for (int off = 32; off > 0; off >>= 1) v += __shfl_down(v, off, 64);
    if ((tid & 63) == 0) sred[tid >> 6] = v;
    __syncthreads();
    if (tid == 0)
        atomicAdd(&ws[WS_SEED8 + b * 8 + (blockIdx.x & 7)],
                  sred[0] + sred[1] + sred[2] + sred[3]);
}

// ---------------- pass 4: lovasz from count histograms (midpoint e) ----------------
__global__ __launch_bounds__(256) void pass4_lovasz(float* __restrict__ ws)
{
    const int t = blockIdx.x;    // (b*16 + iid)
    const int j = threadIdx.x;   // j=0 <-> highest-error bucket
    __shared__ float sF[KB], sB[KB];
    __shared__ double red[KB];

    const float P = ws[WS_STATS + t * 8];
    const float* gh = ws + WS_HIST + (size_t)t * 2 * KB;

    const int k = KB - 1 - j;
    const float nF = gh[k], nB = gh[KB + k];
    const float mid = ((float)k + 0.5f) * (1.f / 128.f);
    const float rF = nF * mid, rB = nB * mid;

    sF[j] = nF; sB[j] = nB;
    __syncthreads();
    for (int off = 1; off < KB; off <<= 1) {
        float a = 0.f, c = 0.f;
        if (j >= off) { a = sF[j - off]; c = sB[j - off]; }
        __syncthreads();
        sF[j] += a; sB[j] += c;
        __syncthreads();
    }
    double contrib = 0.0;
    if (P > 0.f) {   // exists == (cnt > 0)
        const double Bb = (double)sB[j] - (double)nB;
        const double U0 = (double)P + Bb;
        const double Fafter = (double)sF[j];
        contrib = (double)rF / U0
                + (double)rB * ((double)P - Fafter) / (U0 * (U0 + (double)nB));
    }
    red[j] = contrib;
    __syncthreads();
    for (int off = KB / 2; off > 0; off >>= 1) {
        if (j < off) red[j] += red[j + off];
        __syncthreads();
    }
    if (j == 0) ws[WS_INSTL + t] = (float)red[0];
}

// ---------------- pass 5: final assembly (parallel over batches) ----------------
__global__ void pass5_final(const float* __restrict__ ws, float* __restrict__ out)
{
    const int t = threadIdx.x;   // 64 threads
    __shared__ float pl[3][4];
    if (t < 4) {
        float obj = 0.f, v = 0.f, i2 = 0.f;
        for (int i = 0; i < NID; ++i) {
            const int u = t * NID + i;
            const float* s = ws + WS_STATS + (size_t)u * 8;
            const float cnt = s[0];
            i2 += ws[WS_INSTL + u];
            if (cnt > 0.f) {
                obj += 1.f;
                const float m0 = s[4] / cnt, m1 = s[5] / cnt, m2 = s[6] / cnt;
                v += (s[7] - cnt * (m0 * m0 + m1 * m1 + m2 * m2)) / (3.f * cnt);
            }
        }
        float sb = 0.f, bg = 0.f;
        for (int j = 0; j < 8; ++j) {
            sb += ws[WS_SEED8 + t * 8 + j];
            bg += ws[WS_BG8   + t * 8 + j];
        }
        const float denom = fmaxf(obj, 1.f);
        pl[0][t] = i2 / denom;
        pl[1][t] = v / denom;
        pl[2][t] = (sb + bg) / (float)DHW;
    }
    __syncthreads();
    if (t == 0) {
        const float linst = (pl[0][0] + pl[0][1] + pl[0][2] + pl[0][3]) * (1.0f / BB);
        const float lvar  = (pl[1][0] + pl[1][1] + pl[1][2] + pl[1][3]) * (10.0f / BB);
        const float lseed = (pl[2][0] + pl[2][1] + pl[2][2] + pl[2][3]) * (1.0f / BB);
        out[0] = linst;
        out[1] = lvar;
        out[2] = lseed;
        out[3] = linst + lvar + lseed;
    }
}

extern "C" void kernel_launch(void* const* d_in, const int* in_sizes, int n_in,
                              void* d_out, int out_size, void* d_ws, size_t ws_size,
                              hipStream_t stream)
{
    const float* pred   = (const float*)d_in[0];
    const int*   inst   = (const int*)  d_in[1];
    const int*   labels = (const int*)  d_in[2];
    // d_in[3] = center_images (unused), d_in[4] = xyzm (computed analytically)
    float* ws  = (float*)d_ws;
    float* out = (float*)d_out;

    hipMemsetAsync(d_ws, 0, (size_t)WS_TOTAL * sizeof(float), stream);

    dim3 grid1(256, BB);
    dim3 grid3(P3_CHUNKS, BB);
    pass1_stats<<<grid1, 256, 0, stream>>>(pred, inst, labels, ws);
    pass3_hist <<<grid3, 256, 0, stream>>>(pred, inst, ws);
    pass4_lovasz<<<64, KB, 0, stream>>>(ws);
    pass5_final<<<1, 64, 0, stream>>>(ws, out);
}

// Round 5
// 337.373 us; speedup vs baseline: 2.0464x; 1.0441x over previous
//
#include <hip/hip_runtime.h>

#define NID  16
#define BB   4
#define HH   192
#define WW   192
#define DHW  1179648          // 32*192*192
#define KB   256              // lovasz buckets over e in [0,2]

// pass1: grid (256, BB); chunk = 24 rows of 192 = 4608 voxels; 72 iters of 64
#define P1_ROWS   24
#define P1_ITERS  72

// pass3 chunking: 768 blocks (3/CU), chunk 6144 voxels, 6 subs of 1024
#define P3_CHUNKS 192
#define P3_CHUNK  6144        // DHW / 192
#define SUBT      6
#define SUBN      1024        // P3_CHUNK / 6
#define SUBIT     4           // SUBN / 256

// workspace layout (float indices)
#define WS_STATS 0            // [64][8]: cnt, Sx, Sy, Sz, s0, s1, s2, ssq
#define WS_BG8   512          // [4][8] spread slots (same-line atomic chains /8)
#define WS_SEED8 544          // [4][8]
#define WS_INSTL 576          // [64]
#define WS_HIST  640          // [64][2][KB] floats: cntF, cntB
#define WS_TOTAL (640 + 64*2*KB)

__device__ __forceinline__ float ftanh(float x) {
    float t = __expf(2.f * x);
    return 1.f - 2.f / (t + 1.f);
}
__device__ __forceinline__ float fsigmoid(float x) {
    return 1.f / (1.f + __expf(-x));
}
__device__ __forceinline__ float wred(float v) {
    for (int off = 32; off > 0; off >>= 1) v += __shfl_down(v, off, 64);
    return v;
}
// xyzm is a linspace stack: compute from flat index
__device__ __forceinline__ void xyz_of(int v, float& x, float& y, float& z) {
    int w = v % WW;
    int t = v / WW;
    int h = t % HH;
    int d = t / HH;
    x = (float)w * (1.f / 191.f);
    y = (float)h * (1.f / 191.f);
    z = (float)d * (1.f / 31.f);
}

#define REP8(M) M(0) M(1) M(2) M(3) M(4) M(5) M(6) M(7)

// ---------------- pass 1: per-(b,id) masked stats + bg_seed ----------------
// Hot loop: named-scalar register accumulation (no arrays -> no SROA risk).
// Epilogue: per-wave shuffle reduce -> LDS block partial (disjoint slots per
// wave) -> ONE wave-coalesced global atomic of 128 consecutive floats.
// (r3 lesson: 262K lane0-serial scalar atomics onto 32 lines = ~8K-deep
//  memory-side line-RMW chains ~ 245 us. Coalesced: 8 line-RMWs/block.)
__global__ __launch_bounds__(256) void pass1_stats(
    const float* __restrict__ pred, const int* __restrict__ inst,
    const int* __restrict__ labels, float* __restrict__ ws)
{
    __shared__ float part[128];         // [id 0..15][st 0..7] block partials
    const int b    = blockIdx.y;
    const int tid  = threadIdx.x;
    const int wv   = tid >> 6;          // 0..3
    const int lane = tid & 63;
    const int idb0 = (wv & 1) * 8;      // 0-based first id of this wave's half

    const float* p3 = pred + (size_t)(b * 7 + 3) * DHW;
    const int*   ib = inst   + (size_t)b * DHW;
    const int*   lb = labels + (size_t)b * DHW;
    const int row0 = blockIdx.x * P1_ROWS;

    if (wv < 2) {
        // geometry waves: packed ints G0=Sw|cnt<<17, G1=Sh|Sd<<17 per id.
        // ranges (72 iters): cnt<=72, Sw,Sh<=13752<2^17, Sd<=2232 -> exact.
        unsigned G00=0u,G01=0u,G02=0u,G03=0u,G04=0u,G05=0u,G06=0u,G07=0u;
        unsigned G10=0u,G11=0u,G12=0u,G13=0u,G14=0u,G15=0u,G16=0u,G17=0u;
        float bgacc = 0.f;
        for (int it = 0; it < P1_ITERS; ++it) {
            const int seg = it % 3, r = it / 3;     // uniform (SALU)
            const int row = row0 + r;
            const int w   = seg * 64 + lane;
            const int v   = row * WW + w;
            const int id  = ib[v];
            if (wv == 0) {
                const float seed = fsigmoid(p3[3 * DHW + v]);
                if (lb[v] == 0) bgacc += seed * seed;
            }
            const unsigned p0 = (unsigned)w | (1u << 17);
            const unsigned p1 = (unsigned)(row % HH) | ((unsigned)(row / HH) << 17);
            const int idx = id - 1 - idb0;
            #define GEO(Q) { const bool e = (idx == Q); \
                             G0##Q += e ? p0 : 0u; G1##Q += e ? p1 : 0u; }
            REP8(GEO)
            #undef GEO
        }
        #define GRED(Q) { \
            float c  = wred((float)(G0##Q >> 17)); \
            float sx = wred((float)(G0##Q & 0x1FFFFu) * (1.f / 191.f)); \
            float sy = wred((float)(G1##Q & 0x1FFFFu) * (1.f / 191.f)); \
            float sz = wred((float)(G1##Q >> 17)      * (1.f / 31.f)); \
            if (lane == 0) { float* pp = &part[(idb0 + Q) * 8]; \
                             pp[0] = c; pp[1] = sx; pp[2] = sy; pp[3] = sz; } }
        REP8(GRED)
        #undef GRED
        if (wv == 0) {
            const float r = wred(bgacc);
            if (lane == 0) atomicAdd(&ws[WS_BG8 + b * 8 + (blockIdx.x & 7)], r);
        }
    } else {
        // sigma waves: 4 float accumulators per id, named scalars
        float SA0=0.f,SA1=0.f,SA2=0.f,SA3=0.f,SA4=0.f,SA5=0.f,SA6=0.f,SA7=0.f;
        float SB0=0.f,SB1=0.f,SB2=0.f,SB3=0.f,SB4=0.f,SB5=0.f,SB6=0.f,SB7=0.f;
        float SC0=0.f,SC1=0.f,SC2=0.f,SC3=0.f,SC4=0.f,SC5=0.f,SC6=0.f,SC7=0.f;
        float SD0=0.f,SD1=0.f,SD2=0.f,SD3=0.f,SD4=0.f,SD5=0.f,SD6=0.f,SD7=0.f;
        for (int it = 0; it < P1_ITERS; ++it) {
            const int seg = it % 3, r = it / 3;
            const int v   = (row0 + r) * WW + seg * 64 + lane;
            const int id  = ib[v];
            const float s0 = p3[v], s1 = p3[DHW + v], s2 = p3[2 * DHW + v];
            const float sq = s0 * s0 + s1 * s1 + s2 * s2;
            const int idx = id - 1 - idb0;
            #define SIG(Q) { const float m = (idx == Q) ? 1.f : 0.f; \
                SA##Q = fmaf(m, s0, SA##Q); SB##Q = fmaf(m, s1, SB##Q); \
                SC##Q = fmaf(m, s2, SC##Q); SD##Q = fmaf(m, sq, SD##Q); }
            REP8(SIG)
            #undef SIG
        }
        #define SRED(Q) { \
            float r0 = wred(SA##Q), r1 = wred(SB##Q); \
            float r2 = wred(SC##Q), r3 = wred(SD##Q); \
            if (lane == 0) { float* pp = &part[(idb0 + Q) * 8 + 4]; \
                             pp[0] = r0; pp[1] = r1; pp[2] = r2; pp[3] = r3; } }
        REP8(SRED)
        #undef SRED
    }
    __syncthreads();
    // one coalesced atomic covering 128 consecutive floats (8 lines/block)
    if (tid < 128) {
        const float pv = part[tid];
        if (pv != 0.f) atomicAdd(&ws[WS_STATS + b * 128 + tid], pv);
    }
}

// ---------------- pass 3: staged se + count-only histograms ----------------
// r4 counter-driven rework of the atomic pattern:
//  (a) 16-way id rotation: at pass p, slot j, lane l handles
//      iid = (p*4+j+(l&15))&15 -> every atomic instruction covers all 16 ids,
//      each id on 2 lanes per replica (2-way same-address = free, m136).
//  (b) histogram row stride 257 words -> bank = (iid+k)%32: the 16 concurrent
//      ids hit 16 distinct banks (was: stride 256 -> ALL ids same bank,
//      SQ_LDS_BANK_CONFLICT 5.99M cy).
//  (c) SUBN 2304->1024 (LDS 70.6->49.8 KB) + grid 128->192/batch:
//      3 blocks/CU, 12 waves/CU (occupancy 19%->~36%).
__global__ __launch_bounds__(256) void pass3_hist(
    const float* __restrict__ pred, const int* __restrict__ inst,
    float* __restrict__ ws)
{
    __shared__ float4 sev[SUBN];              // 16.4 KB staged (se0,se1,se2,seed|id)
    __shared__ unsigned cntFB[2][NID][KB + 1];// 32.9 KB: x2 replicas, padded stride
    __shared__ float ctrs[NID][8];
    __shared__ float sred[4];

    const int b   = blockIdx.y;
    const int tid = threadIdx.x;
    const int rep = (tid >> 5) & 1;           // half-wave replica
    const int rot = tid & 15;                 // per-lane id rotation (16-way)

    for (int i = tid; i < 2 * NID * (KB + 1); i += 256) ((unsigned*)cntFB)[i] = 0u;
    if (tid < NID) {
        const float* s = ws + WS_STATS + (size_t)(b * NID + tid) * 8;
        const float cnt = s[0];
        const float safe = fmaxf(cnt, 1.f);
        const float m0 = s[4] / safe, m1 = s[5] / safe, m2 = s[6] / safe;
        ctrs[tid][0] = s[1] / safe;
        ctrs[tid][1] = s[2] / safe;
        ctrs[tid][2] = s[3] / safe;
        ctrs[tid][3] = __expf(10.f * m0);
        ctrs[tid][4] = __expf(10.f * m1);
        ctrs[tid][5] = __expf(10.f * m2);
        ctrs[tid][6] = 0.f;
        ctrs[tid][7] = (cnt > 0.f) ? 1.f : 0.f;
    }
    __syncthreads();

    const float* pb = pred + (size_t)b * 7 * DHW;
    const int*   ib = inst + (size_t)b * DHW;

    float sacc = 0.f;
    const int base0 = blockIdx.x * P3_CHUNK;

    for (int sub = 0; sub < SUBT; ++sub) {
        const int vb = base0 + sub * SUBN;
        // ---- phase A: stage se / seed / id ----
        for (int it = 0; it < SUBIT; ++it) {
            const int i = it * 256 + tid;
            const int v = vb + i;
            float x, y, z; xyz_of(v, x, y, z);
            const float se0 = ftanh(pb[v])           + x;
            const float se1 = ftanh(pb[DHW + v])     + y;
            const float se2 = ftanh(pb[2 * DHW + v]) + z;
            const float seed = fsigmoid(pb[6 * DHW + v]);
            const unsigned id = (unsigned)ib[v];
            // pack instance id into low 8 mantissa bits of seed (|err| < 2^-16)
            const unsigned sw = (__float_as_uint(seed) & ~0xFFu) | id;
            sev[i] = make_float4(se0, se1, se2, __uint_as_float(sw));
        }
        __syncthreads();
        // ---- phase B: 4 passes x 4 slots; lane-rotated over ALL 16 ids ----
        for (int p = 0; p < 4; ++p) {
            float cx[4], cy[4], cz[4], e0[4], e1[4], e2[4];
            int iidq[4];
            #pragma unroll
            for (int j = 0; j < 4; ++j) {
                const int iid = (p * 4 + j + rot) & 15;
                iidq[j] = iid;
                cx[j] = ctrs[iid][0]; cy[j] = ctrs[iid][1]; cz[j] = ctrs[iid][2];
                e0[j] = ctrs[iid][3]; e1[j] = ctrs[iid][4]; e2[j] = ctrs[iid][5];
            }
            for (int it = 0; it < SUBIT; ++it) {
                const int i = it * 256 + tid;
                const float4 sv = sev[i];
                const unsigned sw = __float_as_uint(sv.w);
                const int id = (int)(sw & 0xFFu);
                const float seed = sv.w;
                #pragma unroll
                for (int j = 0; j < 4; ++j) {
                    const float d0 = sv.x - cx[j];
                    const float d1 = sv.y - cy[j];
                    const float d2 = sv.z - cz[j];
                    const float q2 = d0 * d0 * e0[j] + d1 * d1 * e1[j] + d2 * d2 * e2[j];
                    const float dist = __expf(-q2);
                    const bool m = (id == iidq[j] + 1);
                    const float e = m ? (2.f - 2.f * dist) : (2.f * dist);
                    int k = (int)(e * 128.f);
                    k = min(max(k, 0), KB - 1);
                    // BG in bucket 0 contributes exactly 0 -> skip
                    const unsigned val = m ? 1u : (k ? 0x10000u : 0u);
                    if (m) { const float ds = seed - dist; sacc += ds * ds; }
                    if (val) atomicAdd(&cntFB[rep][iidq[j]][k], val);
                }
            }
        }
        __syncthreads();   // also guards cntFB before the merge below
    }

    // merge packed LDS counts (both replicas) -> global float histograms
    float* gh = ws + WS_HIST;
    for (int i = tid; i < NID * KB; i += 256) {
        const int iid = i >> 8, k = i & (KB - 1);
        const unsigned c = cntFB[0][iid][k] + cntFB[1][iid][k];  // fields < 2^15: no carry
        float* basep = gh + (size_t)(b * NID + iid) * 2 * KB;
        const float cf = (float)(c & 0xFFFFu);
        const float cb = (float)(c >> 16);
        if (cf != 0.f) atomicAdd(&basep[k], cf);
        if (cb != 0.f) atomicAdd(&basep[KB + k], cb);
    }
    // per-batch seed loss reduce (spread over 8 slots)
    float v = sacc;
    for (int off = 32; off > 0; off >>= 1) v += __shfl_down(v, off, 64);
    if ((tid & 63) == 0) sred[tid >> 6] = v;
    __syncthreads();
    if (tid == 0)
        atomicAdd(&ws[WS_SEED8 + b * 8 + (blockIdx.x & 7)],
                  sred[0] + sred[1] + sred[2] + sred[3]);
}

// ---------------- pass 4: lovasz from count histograms (midpoint e) ----------------
__global__ __launch_bounds__(256) void pass4_lovasz(float* __restrict__ ws)
{
    const int t = blockIdx.x;    // (b*16 + iid)
    const int j = threadIdx.x;   // j=0 <-> highest-error bucket
    __shared__ float sF[KB], sB[KB];
    __shared__ double red[KB];

    const float P = ws[WS_STATS + t * 8];
    const float* gh = ws + WS_HIST + (size_t)t * 2 * KB;

    const int k = KB - 1 - j;
    const float nF = gh[k], nB = gh[KB + k];
    const float mid = ((float)k + 0.5f) * (1.f / 128.f);
    const float rF = nF * mid, rB = nB * mid;

    sF[j] = nF; sB[j] = nB;
    __syncthreads();
    for (int off = 1; off < KB; off <<= 1) {
        float a = 0.f, c = 0.f;
        if (j >= off) { a = sF[j - off]; c = sB[j - off]; }
        __syncthreads();
        sF[j] += a; sB[j] += c;
        __syncthreads();
    }
    double contrib = 0.0;
    if (P > 0.f) {   // exists == (cnt > 0)
        const double Bb = (double)sB[j] - (double)nB;
        const double U0 = (double)P + Bb;
        const double Fafter = (double)sF[j];
        contrib = (double)rF / U0
                + (double)rB * ((double)P - Fafter) / (U0 * (U0 + (double)nB));
    }
    red[j] = contrib;
    __syncthreads();
    for (int off = KB / 2; off > 0; off >>= 1) {
        if (j < off) red[j] += red[j + off];
        __syncthreads();
    }
    if (j == 0) ws[WS_INSTL + t] = (float)red[0];
}

// ---------------- pass 5: final assembly (parallel over batches) ----------------
__global__ void pass5_final(const float* __restrict__ ws, float* __restrict__ out)
{
    const int t = threadIdx.x;   // 64 threads
    __shared__ float pl[3][4];
    if (t < 4) {
        float obj = 0.f, v = 0.f, i2 = 0.f;
        for (int i = 0; i < NID; ++i) {
            const int u = t * NID + i;
            const float* s = ws + WS_STATS + (size_t)u * 8;
            const float cnt = s[0];
            i2 += ws[WS_INSTL + u];
            if (cnt > 0.f) {
                obj += 1.f;
                const float m0 = s[4] / cnt, m1 = s[5] / cnt, m2 = s[6] / cnt;
                v += (s[7] - cnt * (m0 * m0 + m1 * m1 + m2 * m2)) / (3.f * cnt);
            }
        }
        float sb = 0.f, bg = 0.f;
        for (int j = 0; j < 8; ++j) {
            sb += ws[WS_SEED8 + t * 8 + j];
            bg += ws[WS_BG8   + t * 8 + j];
        }
        const float denom = fmaxf(obj, 1.f);
        pl[0][t] = i2 / denom;
        pl[1][t] = v / denom;
        pl[2][t] = (sb + bg) / (float)DHW;
    }
    __syncthreads();
    if (t == 0) {
        const float linst = (pl[0][0] + pl[0][1] + pl[0][2] + pl[0][3]) * (1.0f / BB);
        const float lvar  = (pl[1][0] + pl[1][1] + pl[1][2] + pl[1][3]) * (10.0f / BB);
        const float lseed = (pl[2][0] + pl[2][1] + pl[2][2] + pl[2][3]) * (1.0f / BB);
        out[0] = linst;
        out[1] = lvar;
        out[2] = lseed;
        out[3] = linst + lvar + lseed;
    }
}

extern "C" void kernel_launch(void* const* d_in, const int* in_sizes, int n_in,
                              void* d_out, int out_size, void* d_ws, size_t ws_size,
                              hipStream_t stream)
{
    const float* pred   = (const float*)d_in[0];
    const int*   inst   = (const int*)  d_in[1];
    const int*   labels = (const int*)  d_in[2];
    // d_in[3] = center_images (unused), d_in[4] = xyzm (computed analytically)
    float* ws  = (float*)d_ws;
    float* out = (float*)d_out;

    hipMemsetAsync(d_ws, 0, (size_t)WS_TOTAL * sizeof(float), stream);

    dim3 grid1(256, BB);
    dim3 grid3(P3_CHUNKS, BB);
    pass1_stats<<<grid1, 256, 0, stream>>>(pred, inst, labels, ws);
    pass3_hist <<<grid3, 256, 0, stream>>>(pred, inst, ws);
    pass4_lovasz<<<64, KB, 0, stream>>>(ws);
    pass5_final<<<1, 64, 0, stream>>>(ws, out);
}